// Round 5
// baseline (127.871 us; speedup 1.0000x reference)
//
#include <hip/hip_runtime.h>

constexpr int Bdim = 8192;
constexpr int Ddim = 256;
constexpr int TILE = 256;                   // tile width in columns
constexpr int NT   = Bdim / TILE;           // 32 tiles per side
constexpr int NTRI = NT * (NT + 1) / 2;     // 528 upper-tri tiles
constexpr int RCH  = 8;                     // row chunks per tile
constexpr int RPC  = TILE / RCH;            // 32 rows per chunk (one unit)
constexpr int RPW  = RPC / 4;               // 8 rows per wave
constexpr int NUNIT = NTRI * RCH;           // 4224 units
constexpr int NBLK  = 2048;                 // exactly 8 blocks/CU
constexpr float MARGIN_F = 0.1f;
constexpr double SCALE = 16777216.0;        // 2^24 fixed-point scale

typedef int iv4 __attribute__((ext_vector_type(4)));

// Workspace accumulators (zeroed by k_norm block 0 each call)
struct Acc {
    unsigned long long sum_fix;   // sum * 2^24
    unsigned long long cnt;
    unsigned long long ticket;
};

// d(x,0) = 2*artanh(||x||) = log((1+n)/(1-n)), one wave per row.
// Block 0 thread 0 also zeroes the accumulators for this call.
__global__ __launch_bounds__(256) void k_norm(const float* __restrict__ emb,
                                              float* __restrict__ d,
                                              Acc* __restrict__ acc) {
    if (blockIdx.x == 0 && threadIdx.x == 0) {
        acc->sum_fix = 0ull; acc->cnt = 0ull; acc->ticket = 0ull;
    }
    int row  = blockIdx.x * 4 + (threadIdx.x >> 6);
    int lane = threadIdx.x & 63;
    float4 v = ((const float4*)(emb + (size_t)row * Ddim))[lane];
    float s = v.x * v.x + v.y * v.y + v.z * v.z + v.w * v.w;
#pragma unroll
    for (int off = 32; off > 0; off >>= 1) s += __shfl_down(s, off, 64);
    if (lane == 0) {
        float n = fminf(sqrtf(s), 1.0f - 1e-5f);
        d[row] = logf((1.0f + n) / (1.0f - n));
    }
}

// Grid-stride over 4224 units (32 rows x 256 cols each). Block = 4 waves;
// each wave owns an 8-row strip, each lane an iv4 (4 cols). Non-temporal
// loads for the zero-reuse cmp stream; branchless interior. Deterministic
// integer-atomic accumulation; last-arriving block finalizes out[0].
__global__ __launch_bounds__(256) void k_pairs(const float* __restrict__ d,
                                               const int* __restrict__ cmp,
                                               Acc* __restrict__ acc,
                                               float* __restrict__ out) {
    int tid  = threadIdx.x;
    int lane = tid & 63;
    int wave = tid >> 6;

    float s = 0.0f;
    int cnt = 0;

    for (int u = blockIdx.x; u < NUNIT; u += NBLK) {
        int tri   = u % NTRI;
        int chunk = u / NTRI;
        // decode triangular tile index -> (ti, tj), tj >= ti
        int rem = tri, ti = 0;
        while (rem >= NT - ti) { rem -= NT - ti; ++ti; }
        int tj = ti + rem;

        int i0 = ti * TILE + chunk * RPC + wave * RPW;   // this wave's 8 rows
        int j0 = tj * TILE + lane * 4;                   // 4 consecutive cols
        float4 dj = *(const float4*)(d + j0);
        const iv4* p = (const iv4*)(cmp + (size_t)i0 * Bdim + j0);

        if (ti == tj) {
            // diagonal tile: lanes entirely at/below the diagonal skip the
            // fetch (exec-masked -> whole cache lines not read)
            if (j0 + 3 > i0) {
#pragma unroll
                for (int r = 0; r < RPW; ++r) {
                    int   i  = i0 + r;
                    float di = d[i];
                    iv4   c  = __builtin_nontemporal_load(p);
                    p += Bdim / 4;
                    {
                        bool act = (c.x != 0) & (j0 + 0 > i);
                        float x = fmaf((float)c.x, dj.x - di, MARGIN_F);
                        s += act ? fmaxf(x, 0.0f) : 0.0f; cnt += act ? 1 : 0;
                    }
                    {
                        bool act = (c.y != 0) & (j0 + 1 > i);
                        float x = fmaf((float)c.y, dj.y - di, MARGIN_F);
                        s += act ? fmaxf(x, 0.0f) : 0.0f; cnt += act ? 1 : 0;
                    }
                    {
                        bool act = (c.z != 0) & (j0 + 2 > i);
                        float x = fmaf((float)c.z, dj.z - di, MARGIN_F);
                        s += act ? fmaxf(x, 0.0f) : 0.0f; cnt += act ? 1 : 0;
                    }
                    {
                        bool act = (c.w != 0) & (j0 + 3 > i);
                        float x = fmaf((float)c.w, dj.w - di, MARGIN_F);
                        s += act ? fmaxf(x, 0.0f) : 0.0f; cnt += act ? 1 : 0;
                    }
                }
            }
        } else {
#pragma unroll 4
            for (int r = 0; r < RPW; ++r) {
                float di = d[i0 + r];
                iv4   c  = __builtin_nontemporal_load(p);
                p += Bdim / 4;
                {
                    bool act = (c.x != 0);
                    float x = fmaf((float)c.x, dj.x - di, MARGIN_F);
                    s += act ? fmaxf(x, 0.0f) : 0.0f; cnt += act ? 1 : 0;
                }
                {
                    bool act = (c.y != 0);
                    float x = fmaf((float)c.y, dj.y - di, MARGIN_F);
                    s += act ? fmaxf(x, 0.0f) : 0.0f; cnt += act ? 1 : 0;
                }
                {
                    bool act = (c.z != 0);
                    float x = fmaf((float)c.z, dj.z - di, MARGIN_F);
                    s += act ? fmaxf(x, 0.0f) : 0.0f; cnt += act ? 1 : 0;
                }
                {
                    bool act = (c.w != 0);
                    float x = fmaf((float)c.w, dj.w - di, MARGIN_F);
                    s += act ? fmaxf(x, 0.0f) : 0.0f; cnt += act ? 1 : 0;
                }
            }
        }
    }

#pragma unroll
    for (int off = 32; off > 0; off >>= 1) {
        s   += __shfl_down(s, off, 64);
        cnt += __shfl_down(cnt, off, 64);
    }
    __shared__ float ws_s[4];
    __shared__ int   ws_c[4];
    if ((tid & 63) == 0) { ws_s[wave] = s; ws_c[wave] = cnt; }
    __syncthreads();
    if (tid == 0) {
        float st = ws_s[0] + ws_s[1] + ws_s[2] + ws_s[3];
        int   ct = ws_c[0] + ws_c[1] + ws_c[2] + ws_c[3];
        unsigned long long sfix = (unsigned long long)((double)st * SCALE + 0.5);
        atomicAdd(&acc->sum_fix, sfix);
        atomicAdd(&acc->cnt, (unsigned long long)ct);
        __threadfence();
        unsigned long long t = atomicAdd(&acc->ticket, 1ull);
        if (t == (unsigned long long)(NBLK - 1)) {
            // last block: all adds are globally visible (each preceded by fence)
            unsigned long long S = atomicAdd(&acc->sum_fix, 0ull);
            unsigned long long C = atomicAdd(&acc->cnt, 0ull);
            out[0] = C ? (float)(((double)S / SCALE) / (double)C) : 0.0f;
        }
    }
}

extern "C" void kernel_launch(void* const* d_in, const int* in_sizes, int n_in,
                              void* d_out, int out_size, void* d_ws, size_t ws_size,
                              hipStream_t stream) {
    const float* emb = (const float*)d_in[0];
    const int*   cmp = (const int*)d_in[1];
    float* out = (float*)d_out;

    char* ws = (char*)d_ws;
    Acc*   acc  = (Acc*)ws;                 // 24 B
    float* dvec = (float*)(ws + 256);       // 8192 * 4 B, aligned past acc

    hipLaunchKernelGGL(k_norm, dim3(Bdim / 4), dim3(256), 0, stream,
                       emb, dvec, acc);
    hipLaunchKernelGGL(k_pairs, dim3(NBLK), dim3(256), 0, stream,
                       dvec, cmp, acc, out);
}

// Round 6
// 34.690 us; speedup vs baseline: 3.6862x; 3.6862x over previous
//
#include <hip/hip_runtime.h>

constexpr int Bdim = 8192;
constexpr int Ddim = 256;
constexpr int TS   = 512;                   // tile side (square tiles)
constexpr int NTt  = Bdim / TS;             // 16 tiles per side
constexpr int NTRI = NTt * (NTt + 1) / 2;   // 136 upper-tri tiles
constexpr int RPU  = 16;                    // rows per unit
constexpr int CPT  = TS / RPU;              // 32 chunks per tile
constexpr int NUNIT = NTRI * CPT;           // 4352 = 17 * 256 (perfect CU balance)
constexpr int NBLK  = 2048;                 // 8 blocks/CU resident
constexpr int RPW   = RPU / 4;              // 4 rows per wave
constexpr float MARGIN_F = 0.1f;

typedef int iv4 __attribute__((ext_vector_type(4)));

// d(x,0) = 2*artanh(||x||) = log((1+n)/(1-n)), one wave per row
__global__ __launch_bounds__(256) void k_norm(const float* __restrict__ emb,
                                              float* __restrict__ d) {
    int row  = blockIdx.x * 4 + (threadIdx.x >> 6);
    int lane = threadIdx.x & 63;
    float4 v = ((const float4*)(emb + (size_t)row * Ddim))[lane];
    float s = v.x * v.x + v.y * v.y + v.z * v.z + v.w * v.w;
#pragma unroll
    for (int off = 32; off > 0; off >>= 1) s += __shfl_down(s, off, 64);
    if (lane == 0) {
        float n = fminf(sqrtf(s), 1.0f - 1e-5f);
        d[row] = logf((1.0f + n) / (1.0f - n));
    }
}

// Grid-stride over 4352 units (16 rows x 512 cols each) of the upper-tri
// tile set. Block = 4 waves; each wave owns 4 rows; per row it issues two
// adjacent 1 KiB wave-loads (2 KiB contiguous). Branchless interior.
// Unit count 4352 = 17*256: with round-robin dispatch, every CU gets
// exactly 17 units -> no static tail.
__global__ __launch_bounds__(256) void k_pairs(const float* __restrict__ d,
                                               const int* __restrict__ cmp,
                                               double* __restrict__ psum,
                                               unsigned int* __restrict__ pcnt) {
    int tid  = threadIdx.x;
    int lane = tid & 63;
    int wave = tid >> 6;

    float s = 0.0f;
    int cnt = 0;

    for (int u = blockIdx.x; u < NUNIT; u += NBLK) {
        int tri   = u % NTRI;
        int chunk = u / NTRI;
        // decode triangular tile index -> (ti, tj), tj >= ti
        int rem = tri, ti = 0;
        while (rem >= NTt - ti) { rem -= NTt - ti; ++ti; }
        int tj = ti + rem;

        int i0 = ti * TS + chunk * RPU + wave * RPW;   // this wave's 4 rows
        int j0 = tj * TS + lane * 4;                   // window0 cols
        int j1 = j0 + 256;                             // window1 cols
        float4 dj0 = *(const float4*)(d + j0);
        float4 dj1 = *(const float4*)(d + j1);
        const iv4* p = (const iv4*)(cmp + (size_t)i0 * Bdim + j0);

        if (ti == tj) {
#pragma unroll
            for (int r = 0; r < RPW; ++r) {
                int   i  = i0 + r;
                float di = d[i];
                const iv4* pr = p + (size_t)r * (Bdim / 4);
                if (j0 + 3 > i) {              // whole-vector above diagonal?
                    iv4 c = pr[0];
                    {
                        bool act = (c.x != 0) & (j0 + 0 > i);
                        float x = fmaf((float)c.x, dj0.x - di, MARGIN_F);
                        s += act ? fmaxf(x, 0.0f) : 0.0f; cnt += act ? 1 : 0;
                    }
                    {
                        bool act = (c.y != 0) & (j0 + 1 > i);
                        float x = fmaf((float)c.y, dj0.y - di, MARGIN_F);
                        s += act ? fmaxf(x, 0.0f) : 0.0f; cnt += act ? 1 : 0;
                    }
                    {
                        bool act = (c.z != 0) & (j0 + 2 > i);
                        float x = fmaf((float)c.z, dj0.z - di, MARGIN_F);
                        s += act ? fmaxf(x, 0.0f) : 0.0f; cnt += act ? 1 : 0;
                    }
                    {
                        bool act = (c.w != 0) & (j0 + 3 > i);
                        float x = fmaf((float)c.w, dj0.w - di, MARGIN_F);
                        s += act ? fmaxf(x, 0.0f) : 0.0f; cnt += act ? 1 : 0;
                    }
                }
                if (j1 + 3 > i) {
                    iv4 c = pr[64];            // +256 ints
                    {
                        bool act = (c.x != 0) & (j1 + 0 > i);
                        float x = fmaf((float)c.x, dj1.x - di, MARGIN_F);
                        s += act ? fmaxf(x, 0.0f) : 0.0f; cnt += act ? 1 : 0;
                    }
                    {
                        bool act = (c.y != 0) & (j1 + 1 > i);
                        float x = fmaf((float)c.y, dj1.y - di, MARGIN_F);
                        s += act ? fmaxf(x, 0.0f) : 0.0f; cnt += act ? 1 : 0;
                    }
                    {
                        bool act = (c.z != 0) & (j1 + 2 > i);
                        float x = fmaf((float)c.z, dj1.z - di, MARGIN_F);
                        s += act ? fmaxf(x, 0.0f) : 0.0f; cnt += act ? 1 : 0;
                    }
                    {
                        bool act = (c.w != 0) & (j1 + 3 > i);
                        float x = fmaf((float)c.w, dj1.w - di, MARGIN_F);
                        s += act ? fmaxf(x, 0.0f) : 0.0f; cnt += act ? 1 : 0;
                    }
                }
            }
        } else {
#pragma unroll
            for (int r = 0; r < RPW; ++r) {
                float di = d[i0 + r];
                const iv4* pr = p + (size_t)r * (Bdim / 4);
                iv4 c0 = pr[0];
                iv4 c1 = pr[64];
                {
                    bool act = (c0.x != 0);
                    float x = fmaf((float)c0.x, dj0.x - di, MARGIN_F);
                    s += act ? fmaxf(x, 0.0f) : 0.0f; cnt += act ? 1 : 0;
                }
                {
                    bool act = (c0.y != 0);
                    float x = fmaf((float)c0.y, dj0.y - di, MARGIN_F);
                    s += act ? fmaxf(x, 0.0f) : 0.0f; cnt += act ? 1 : 0;
                }
                {
                    bool act = (c0.z != 0);
                    float x = fmaf((float)c0.z, dj0.z - di, MARGIN_F);
                    s += act ? fmaxf(x, 0.0f) : 0.0f; cnt += act ? 1 : 0;
                }
                {
                    bool act = (c0.w != 0);
                    float x = fmaf((float)c0.w, dj0.w - di, MARGIN_F);
                    s += act ? fmaxf(x, 0.0f) : 0.0f; cnt += act ? 1 : 0;
                }
                {
                    bool act = (c1.x != 0);
                    float x = fmaf((float)c1.x, dj1.x - di, MARGIN_F);
                    s += act ? fmaxf(x, 0.0f) : 0.0f; cnt += act ? 1 : 0;
                }
                {
                    bool act = (c1.y != 0);
                    float x = fmaf((float)c1.y, dj1.y - di, MARGIN_F);
                    s += act ? fmaxf(x, 0.0f) : 0.0f; cnt += act ? 1 : 0;
                }
                {
                    bool act = (c1.z != 0);
                    float x = fmaf((float)c1.z, dj1.z - di, MARGIN_F);
                    s += act ? fmaxf(x, 0.0f) : 0.0f; cnt += act ? 1 : 0;
                }
                {
                    bool act = (c1.w != 0);
                    float x = fmaf((float)c1.w, dj1.w - di, MARGIN_F);
                    s += act ? fmaxf(x, 0.0f) : 0.0f; cnt += act ? 1 : 0;
                }
            }
        }
    }

#pragma unroll
    for (int off = 32; off > 0; off >>= 1) {
        s   += __shfl_down(s, off, 64);
        cnt += __shfl_down(cnt, off, 64);
    }
    __shared__ float ws_s[4];
    __shared__ int   ws_c[4];
    if ((tid & 63) == 0) { ws_s[wave] = s; ws_c[wave] = cnt; }
    __syncthreads();
    if (tid == 0) {
        float st = ws_s[0] + ws_s[1] + ws_s[2] + ws_s[3];
        int   ct = ws_c[0] + ws_c[1] + ws_c[2] + ws_c[3];
        psum[blockIdx.x] = (double)st;
        pcnt[blockIdx.x] = (unsigned int)ct;
    }
}

__global__ __launch_bounds__(256) void k_final(const double* __restrict__ psum,
                                               const unsigned int* __restrict__ pcnt,
                                               float* __restrict__ out) {
    int tid = threadIdx.x;
    double s = 0.0;
    unsigned long long c = 0;
    for (int idx = tid; idx < NBLK; idx += 256) {
        s += psum[idx];
        c += pcnt[idx];
    }
#pragma unroll
    for (int off = 32; off > 0; off >>= 1) {
        s += __shfl_down(s, off, 64);
        c += __shfl_down(c, off, 64);
    }
    __shared__ double sd[4];
    __shared__ unsigned long long sc[4];
    int wave = tid >> 6;
    if ((tid & 63) == 0) { sd[wave] = s; sc[wave] = c; }
    __syncthreads();
    if (tid == 0) {
        double st = sd[0] + sd[1] + sd[2] + sd[3];
        unsigned long long ct = sc[0] + sc[1] + sc[2] + sc[3];
        out[0] = (ct > 0) ? (float)(st / (double)ct) : 0.0f;
    }
}

extern "C" void kernel_launch(void* const* d_in, const int* in_sizes, int n_in,
                              void* d_out, int out_size, void* d_ws, size_t ws_size,
                              hipStream_t stream) {
    const float* emb = (const float*)d_in[0];
    const int*   cmp = (const int*)d_in[1];
    float* out = (float*)d_out;

    char* ws = (char*)d_ws;
    float*        dvec = (float*)ws;                              // 8192 * 4 B
    double*       psum = (double*)(ws + 32768);                   // 2048 * 8 B
    unsigned int* pcnt = (unsigned int*)(ws + 32768 + NBLK * 8);  // 2048 * 4 B

    hipLaunchKernelGGL(k_norm, dim3(Bdim / 4), dim3(256), 0, stream, emb, dvec);
    hipLaunchKernelGGL(k_pairs, dim3(NBLK), dim3(256), 0, stream,
                       dvec, cmp, psum, pcnt);
    hipLaunchKernelGGL(k_final, dim3(1), dim3(256), 0, stream, psum, pcnt, out);
}